// Round 6
// baseline (617.817 us; speedup 1.0000x reference)
//
#include <hip/hip_runtime.h>
#include <hip/hip_bf16.h>
#include <math.h>

// ---------------------------------------------------------------------------
// CrossAttnMLP for gfx950 — cooperative 64-row blocks.
// R6: phase 1 loads x fp32 and converts IN-LOOP (no prefetch register buffers
// at all). R4/R5 lesson: any multi-tile register prefetch buffer spills to
// scratch (R5: 80 MB of scratch writes, 313 B/thread = exactly cA+cB).
//  k0: weights fp32->bf16 + zero BN stat slices
//  k1: x -> transformer body -> h1 frags + BN1 sliced stats
//  k2: BN1+gelu -> h2 GEMM -> h2 frags + BN2 sliced stats
//  k3: BN2+gelu -> final dot
// ---------------------------------------------------------------------------

typedef __attribute__((ext_vector_type(8))) __bf16 bf16x8;
typedef __attribute__((ext_vector_type(2))) __bf16 bf16x2;
typedef __attribute__((ext_vector_type(8))) short s16x8;
typedef __attribute__((ext_vector_type(4))) float f32x4;

union S8U { s16x8 s; bf16x8 b; int i[4]; };

#if defined(__has_builtin)
#if __has_builtin(__builtin_amdgcn_cvt_pk_bf16_f32)
#define HAVE_PK_BF16 1
#endif
#endif

__device__ __forceinline__ short f2b(float f) {
  union { float f; unsigned u; } v; v.f = f;
  unsigned r = v.u + 0x7fffu + ((v.u >> 16) & 1u);   // RNE
  return (short)(r >> 16);
}
__device__ __forceinline__ float b2f(short s) {
  union { unsigned u; float f; } v; v.u = ((unsigned)(unsigned short)s) << 16;
  return v.f;
}
__device__ __forceinline__ int cvt2(float lo, float hi) {
#ifdef HAVE_PK_BF16
  union { bf16x2 v; int i; } u;
  u.v = __builtin_amdgcn_cvt_pk_bf16_f32(lo, hi);
  return u.i;
#else
  return ((int)(unsigned short)f2b(lo)) | (((int)(unsigned short)f2b(hi)) << 16);
#endif
}
// tanh-form gelu, branch-free
__device__ __forceinline__ float gelu_f(float x) {
  float u = x * (0.7978845608028654f + 0.035677408136300125f * x * x);
  float e = __expf(2.0f * u);
  float t = 1.0f - 2.0f / (e + 1.0f);
  return 0.5f * x * (1.0f + t);
}

__device__ __forceinline__ f32x4 mfma_bf16(const S8U& a, const S8U& b, f32x4 c) {
  return __builtin_amdgcn_mfma_f32_16x16x32_bf16(a.b, b.b, c, 0, 0, 0);
}

template<int NC>
__device__ __forceinline__ void zero_acc4(f32x4 (&acc)[4][NC]) {
  f32x4 z = {0.f, 0.f, 0.f, 0.f};
#pragma unroll
  for (int mt = 0; mt < 4; ++mt)
#pragma unroll
    for (int n = 0; n < NC; ++n) acc[mt][n] = z;
}

// acc[mt][n] += act(64x128 LDS, stride 136) @ W^T.
// W row-major (out,k) bf16; out col = wc0 + 16n + l16, k = kw0 + 32kt + 8q..
template<int NC>
__device__ __forceinline__ void gemm4(const short* act,
                                      const short* __restrict__ W, int ldw,
                                      int wc0, int kw0, int l16, int q,
                                      f32x4 (&acc)[4][NC]) {
  const short* Wp = W + (size_t)(wc0 + l16) * ldw + kw0 + 8 * q;
  const short* ap = act + l16 * 136 + 8 * q;
#pragma unroll
  for (int kt = 0; kt < 4; ++kt) {
    S8U a[4];
#pragma unroll
    for (int mt = 0; mt < 4; ++mt)
      a[mt].s = *(const s16x8*)(ap + mt * 16 * 136 + 32 * kt);
#pragma unroll
    for (int n = 0; n < NC; ++n) {
      S8U b; b.s = *(const s16x8*)(Wp + (size_t)(16 * n) * ldw + 32 * kt);
#pragma unroll
      for (int mt = 0; mt < 4; ++mt) acc[mt][n] = mfma_bf16(a[mt], b, acc[mt][n]);
    }
  }
}

// C-layout (row=16mt+4q+r, col=32w+16n+l16) -> row-major LDS, +bias, opt gelu.
__device__ __forceinline__ void store_c4(const f32x4 (&acc)[4][2], const float* __restrict__ bias,
                                         short* dst, int w, int l16, int q, bool do_gelu) {
#pragma unroll
  for (int n = 0; n < 2; ++n) {
    int col = 32 * w + 16 * n + l16;
    float bb = bias[col];
#pragma unroll
    for (int mt = 0; mt < 4; ++mt)
#pragma unroll
      for (int r = 0; r < 4; ++r) {
        float v = acc[mt][n][r] + bb;
        if (do_gelu) v = gelu_f(v);
        dst[(16 * mt + 4 * q + r) * 136 + col] = f2b(v);
      }
  }
}

// acc += bias + residual(buf); LayerNorm over 128 cols; write back to buf.
// Cross-wave row stats flow through the pad columns (col 128..135) of U/V
// (partials, 2 floats per wave) and S1 (mu/rsigma) — no dedicated LDS.
__device__ __forceinline__ void res_ln4(f32x4 (&acc)[4][2], const float* __restrict__ bias,
                                        short* buf, const float* __restrict__ g,
                                        const float* __restrict__ bt,
                                        short* U, short* V, short* S1,
                                        int w, int l16, int q, int tid) {
  float bv0 = bias[32 * w + l16], bv1 = bias[32 * w + 16 + l16];
#pragma unroll
  for (int mt = 0; mt < 4; ++mt)
#pragma unroll
    for (int r = 0; r < 4; ++r) {
      int row = 16 * mt + 4 * q + r;
      acc[mt][0][r] += bv0 + b2f(buf[row * 136 + 32 * w + l16]);
      acc[mt][1][r] += bv1 + b2f(buf[row * 136 + 32 * w + 16 + l16]);
    }
#pragma unroll
  for (int mt = 0; mt < 4; ++mt)
#pragma unroll
    for (int r = 0; r < 4; ++r) {
      float v0 = acc[mt][0][r], v1 = acc[mt][1][r];
      float s = v0 + v1, sq = v0 * v0 + v1 * v1;
#pragma unroll
      for (int m = 1; m < 16; m <<= 1) { s += __shfl_xor(s, m); sq += __shfl_xor(sq, m); }
      if (l16 == 0) {
        int row = 16 * mt + 4 * q + r;
        float* pad = (float*)((w < 2 ? U : V) + row * 136 + 128);
        pad[(w & 1) * 2] = s;
        pad[(w & 1) * 2 + 1] = sq;
      }
    }
  __syncthreads();
  if (tid < 64) {
    const float* up = (const float*)(U + tid * 136 + 128);
    const float* vp = (const float*)(V + tid * 136 + 128);
    float s = up[0] + up[2] + vp[0] + vp[2];
    float sq = up[1] + up[3] + vp[1] + vp[3];
    float mu = s * (1.0f / 128.0f);
    float var = sq * (1.0f / 128.0f) - mu * mu;
    float* sp = (float*)(S1 + tid * 136 + 128);
    sp[0] = mu;
    sp[1] = rsqrtf(var + 1e-5f);
  }
  __syncthreads();
  float gg0 = g[32 * w + l16], bb0 = bt[32 * w + l16];
  float gg1 = g[32 * w + 16 + l16], bb1 = bt[32 * w + 16 + l16];
#pragma unroll
  for (int mt = 0; mt < 4; ++mt)
#pragma unroll
    for (int r = 0; r < 4; ++r) {
      int row = 16 * mt + 4 * q + r;
      const float* sp = (const float*)(S1 + row * 136 + 128);
      float mu = sp[0], rs = sp[1];
      buf[row * 136 + 32 * w + l16]      = f2b((acc[mt][0][r] - mu) * rs * gg0 + bb0);
      buf[row * 136 + 32 * w + 16 + l16] = f2b((acc[mt][1][r] - mu) * rs * gg1 + bb1);
    }
  __syncthreads();
}

// FFN: act = LN(act + W2 @ gelu(W1 @ act + b1) + b2), 128-col chunks via S1.
__device__ __forceinline__ void ffn4(short* act, short* S1, short* U, short* V,
                                     const short* __restrict__ w1, const float* __restrict__ b1,
                                     const short* __restrict__ w2, const float* __restrict__ b2,
                                     const float* __restrict__ g, const float* __restrict__ bt,
                                     int w, int l16, int q, int tid) {
  f32x4 acc2[4][2];
  zero_acc4(acc2);
#pragma unroll 1
  for (int c = 0; c < 4; ++c) {
    f32x4 h[4][2];
    zero_acc4(h);
    gemm4<2>(act, w1, 128, 128 * c + 32 * w, 0, l16, q, h);
    store_c4(h, b1 + 128 * c, S1, w, l16, q, true);
    __syncthreads();
    gemm4<2>(S1, w2, 512, 32 * w, 128 * c, l16, q, acc2);
    __syncthreads();
  }
  res_ln4(acc2, b2, act, g, bt, U, V, S1, w, l16, q, tid);
}

// ---------------------------------------------------------------------------
struct K1Args {
  const float* x;
  const short *wpep, *wtcr, *wvp, *wop, *wvt, *wot, *w1p, *w2p, *w1t, *w2t, *wh1;
  const float *bpep, *btcr, *bvp, *bop, *bvt, *bot;
  const float *g1p, *e1p, *g2p, *e2p, *g1t, *e1t, *g2t, *e2t;
  const float *b1p, *b2p, *b1t, *b2t, *bh1;
  float* stats;
  short* h1f;
};

__global__ __launch_bounds__(256, 3) void k1_body(K1Args A) {
  __shared__ __align__(16) short L[3 * 64 * 136];   // 52224 B -> 3 blocks/CU
  short* U = L;
  short* V = L + 64 * 136;
  short* S1 = L + 2 * 64 * 136;
  const int tid = threadIdx.x;
  const int w = tid >> 6, lane = tid & 63, l16 = lane & 15, q = lane >> 4;
  const size_t R0 = (size_t)blockIdx.x * 64;

  // ---- phase 1: x -> pep(U), tcr(V) ----
  // A-frags built from global fp32 IN-LOOP: 8 transient float4 + 4 frags per
  // iteration, no persistent prefetch buffers -> no scratch spill. unroll 2
  // lets the scheduler overlap next iteration's loads with MFMAs.
  f32x4 acc[4][2];
  const float* xbase = A.x + (R0 + l16) * 864 + 8 * q;

  zero_acc4(acc);
  const short* Wp1 = A.wpep + (size_t)(32 * w + l16) * 384 + 8 * q;
#pragma unroll 2
  for (int t = 0; t < 12; ++t) {
    S8U a[4];
#pragma unroll
    for (int mt = 0; mt < 4; ++mt) {
      const float* p = xbase + mt * (16 * 864) + 32 * t;
      float4 f0 = *(const float4*)p;
      float4 f1 = *(const float4*)(p + 4);
      union { s16x8 s; int i[4]; } u;
      u.i[0] = cvt2(f0.x, f0.y);
      u.i[1] = cvt2(f0.z, f0.w);
      u.i[2] = cvt2(f1.x, f1.y);
      u.i[3] = cvt2(f1.z, f1.w);
      a[mt].s = u.s;
    }
#pragma unroll
    for (int n = 0; n < 2; ++n) {
      S8U b; b.s = *(const s16x8*)(Wp1 + (size_t)(16 * n) * 384 + 32 * t);
#pragma unroll
      for (int mt = 0; mt < 4; ++mt) acc[mt][n] = mfma_bf16(a[mt], b, acc[mt][n]);
    }
  }
  store_c4(acc, A.bpep, U, w, l16, q, false);

  zero_acc4(acc);
  const short* Wp2 = A.wtcr + (size_t)(32 * w + l16) * 480 + 8 * q;
#pragma unroll 2
  for (int t = 0; t < 15; ++t) {
    S8U a[4];
#pragma unroll
    for (int mt = 0; mt < 4; ++mt) {
      const float* p = xbase + mt * (16 * 864) + 384 + 32 * t;
      float4 f0 = *(const float4*)p;
      float4 f1 = *(const float4*)(p + 4);
      union { s16x8 s; int i[4]; } u;
      u.i[0] = cvt2(f0.x, f0.y);
      u.i[1] = cvt2(f0.z, f0.w);
      u.i[2] = cvt2(f1.x, f1.y);
      u.i[3] = cvt2(f1.z, f1.w);
      a[mt].s = u.s;
    }
#pragma unroll
    for (int n = 0; n < 2; ++n) {
      S8U b; b.s = *(const s16x8*)(Wp2 + (size_t)(16 * n) * 480 + 32 * t);
#pragma unroll
      for (int mt = 0; mt < 4; ++mt) acc[mt][n] = mfma_bf16(a[mt], b, acc[mt][n]);
    }
  }
  store_c4(acc, A.btcr, V, w, l16, q, false);
  __syncthreads();                            // U, V complete

  // ---- phase 2: attention-equivalent projections + LN ----
  f32x4 accT[4][2];
  zero_acc4(acc);
  gemm4<2>(U, A.wvt, 128, 32 * w, 0, l16, q, acc);     // H = pep @ wv_t2p^T
  store_c4(acc, A.bvt, S1, w, l16, q, false);
  zero_acc4(accT);
  gemm4<2>(V, A.wvp, 128, 32 * w, 0, l16, q, accT);    // T = tcr @ wv_p2t^T (held)
  __syncthreads();                            // S1(H) complete
  zero_acc4(acc);
  gemm4<2>(S1, A.wot, 128, 32 * w, 0, l16, q, acc);
  res_ln4(acc, A.bot, V, A.g1t, A.e1t, U, V, S1, w, l16, q, tid);   // V = ta
  store_c4(accT, A.bvp, S1, w, l16, q, false);
  __syncthreads();                            // S1(T) complete
  zero_acc4(acc);
  gemm4<2>(S1, A.wop, 128, 32 * w, 0, l16, q, acc);
  res_ln4(acc, A.bop, U, A.g1p, A.e1p, U, V, S1, w, l16, q, tid);   // U = pa

  // ---- phase 3: FFNs ----
  ffn4(U, S1, U, V, A.w1p, A.b1p, A.w2p, A.b2p, A.g2p, A.e2p, w, l16, q, tid);
  ffn4(V, S1, U, V, A.w1t, A.b1t, A.w2t, A.b2t, A.g2t, A.e2t, w, l16, q, tid);

  // ---- phase 4: h1 = [pa|ta] @ w_h1^T + b ; frag store + BN1 stats ----
  zero_acc4(acc);
  gemm4<2>(U, A.wh1, 256, 32 * w, 0, l16, q, acc);
  gemm4<2>(V, A.wh1, 256, 32 * w, 128, l16, q, acc);

  const int slice = (int)blockIdx.x & 15;
  union { s16x8 v8[4]; int i[16]; } ob;
#pragma unroll
  for (int n = 0; n < 2; ++n) {
    int col = 32 * w + 16 * n + l16;
    float bb = A.bh1[col];
    float ss = 0.f, qq = 0.f;
#pragma unroll
    for (int mt = 0; mt < 4; ++mt) {
      float v0 = acc[mt][n][0] + bb, v1 = acc[mt][n][1] + bb;
      float v2 = acc[mt][n][2] + bb, v3 = acc[mt][n][3] + bb;
      ss += (v0 + v1) + (v2 + v3);
      qq += (v0 * v0 + v1 * v1) + (v2 * v2 + v3 * v3);
      ob.i[mt * 4 + n * 2 + 0] = cvt2(v0, v1);        // shorts idx mt*8+n*4+{0,1}
      ob.i[mt * 4 + n * 2 + 1] = cvt2(v2, v3);        // shorts idx mt*8+n*4+{2,3}
    }
    ss += __shfl_xor(ss, 16); qq += __shfl_xor(qq, 16);
    ss += __shfl_xor(ss, 32); qq += __shfl_xor(qq, 32);
    if (q == 0) {
      atomicAdd(&A.stats[slice * 128 + col], ss);
      atomicAdd(&A.stats[2048 + slice * 128 + col], qq);
    }
  }
  short* hf = A.h1f + (size_t)blockIdx.x * 8192 + w * 2048 + lane * 32;
#pragma unroll
  for (int j = 0; j < 4; ++j) *(s16x8*)(hf + 8 * j) = ob.v8[j];
}

// ---------------------------------------------------------------------------
struct K2Args {
  const short* h1f;
  const short* wh2;
  const float *bh2, *bn1g, *bn1b;
  float* stats;
  short* h2f;
};

__global__ __launch_bounds__(256, 4) void k2_mid(K2Args A) {
  __shared__ __align__(16) short U[64 * 136];
  __shared__ float s1[128], t1[128];
  const int tid = threadIdx.x;
  const int w = tid >> 6, lane = tid & 63, l16 = lane & 15, q = lane >> 4;

  if (tid < 128) {
    float S = 0.f, Q = 0.f;
#pragma unroll
    for (int s = 0; s < 16; ++s) {
      S += A.stats[s * 128 + tid];
      Q += A.stats[2048 + s * 128 + tid];
    }
    float mu = S * (1.0f / 65536.0f);
    float var = Q * (1.0f / 65536.0f) - mu * mu;
    float sc = A.bn1g[tid] * rsqrtf(var + 1e-5f);
    s1[tid] = sc;
    t1[tid] = A.bn1b[tid] - mu * sc;
  }
  __syncthreads();

  const short* hf = A.h1f + (size_t)blockIdx.x * 8192 + w * 2048 + lane * 32;
  union { s16x8 v8[4]; short sh[32]; } ib;
#pragma unroll
  for (int j = 0; j < 4; ++j) ib.v8[j] = *(const s16x8*)(hf + 8 * j);
#pragma unroll
  for (int n = 0; n < 2; ++n) {
    int col = 32 * w + 16 * n + l16;
    float sc = s1[col], tc = t1[col];
#pragma unroll
    for (int mt = 0; mt < 4; ++mt)
#pragma unroll
      for (int r = 0; r < 4; ++r) {
        float f = gelu_f(b2f(ib.sh[mt * 8 + n * 4 + r]) * sc + tc);
        U[(16 * mt + 4 * q + r) * 136 + col] = f2b(f);
      }
  }
  __syncthreads();

  f32x4 acc[4][1];
  zero_acc4(acc);
  gemm4<1>(U, A.wh2, 128, 16 * w, 0, l16, q, acc);

  const int slice = (int)blockIdx.x & 15;
  int col = 16 * w + l16;
  float bb = A.bh2[col];
  float ss = 0.f, qq = 0.f;
  union { s16x8 v8[2]; int i[8]; } ob;
#pragma unroll
  for (int mt = 0; mt < 4; ++mt) {
    float v0 = acc[mt][0][0] + bb, v1 = acc[mt][0][1] + bb;
    float v2 = acc[mt][0][2] + bb, v3 = acc[mt][0][3] + bb;
    ss += (v0 + v1) + (v2 + v3);
    qq += (v0 * v0 + v1 * v1) + (v2 * v2 + v3 * v3);
    ob.i[mt * 2 + 0] = cvt2(v0, v1);
    ob.i[mt * 2 + 1] = cvt2(v2, v3);
  }
  ss += __shfl_xor(ss, 16); qq += __shfl_xor(qq, 16);
  ss += __shfl_xor(ss, 32); qq += __shfl_xor(qq, 32);
  if (q == 0) {
    atomicAdd(&A.stats[4096 + slice * 64 + col], ss);
    atomicAdd(&A.stats[5120 + slice * 64 + col], qq);
  }
  short* of = A.h2f + (size_t)blockIdx.x * 4096 + w * 1024 + lane * 16;
  *(s16x8*)of = ob.v8[0];
  *(s16x8*)(of + 8) = ob.v8[1];
}

// ---------------------------------------------------------------------------
struct K3Args {
  const short* h2f;
  const float *bn2g, *bn2b;
  const float* stats;
  const float *wout, *bout;
  float* out;
};

__global__ __launch_bounds__(256, 4) void k3_out(K3Args A) {
  __shared__ float s2[64], t2[64], wo[64];
  __shared__ float part[4][64];
  const int tid = threadIdx.x;
  const int w = tid >> 6, lane = tid & 63, l16 = lane & 15, q = lane >> 4;

  if (tid < 64) {
    float S = 0.f, Q = 0.f;
#pragma unroll
    for (int s = 0; s < 16; ++s) {
      S += A.stats[4096 + s * 64 + tid];
      Q += A.stats[5120 + s * 64 + tid];
    }
    float mu = S * (1.0f / 65536.0f);
    float var = Q * (1.0f / 65536.0f) - mu * mu;
    float sc = A.bn2g[tid] * rsqrtf(var + 1e-5f);
    s2[tid] = sc;
    t2[tid] = A.bn2b[tid] - mu * sc;
    wo[tid] = A.wout[tid];
  }
  __syncthreads();

  const short* hf = A.h2f + (size_t)blockIdx.x * 4096 + w * 1024 + lane * 16;
  union { s16x8 v8[2]; short sh[16]; } ib;
  ib.v8[0] = *(const s16x8*)hf;
  ib.v8[1] = *(const s16x8*)(hf + 8);
  int col = 16 * w + l16;
  float sc = s2[col], tc = t2[col], wc = wo[col];
  float rv[4][4];
#pragma unroll
  for (int mt = 0; mt < 4; ++mt)
#pragma unroll
    for (int r = 0; r < 4; ++r)
      rv[mt][r] = gelu_f(b2f(ib.sh[mt * 4 + r]) * sc + tc) * wc;
#pragma unroll
  for (int mt = 0; mt < 4; ++mt)
#pragma unroll
    for (int r = 0; r < 4; ++r) {
#pragma unroll
      for (int m = 1; m < 16; m <<= 1) rv[mt][r] += __shfl_xor(rv[mt][r], m);
    }
  if (l16 == 0) {
#pragma unroll
    for (int mt = 0; mt < 4; ++mt)
#pragma unroll
      for (int r = 0; r < 4; ++r) part[w][16 * mt + 4 * q + r] = rv[mt][r];
  }
  __syncthreads();
  if (tid < 64)
    A.out[(size_t)blockIdx.x * 64 + tid] =
        part[0][tid] + part[1][tid] + part[2][tid] + part[3][tid] + A.bout[0];
}

// ---------------------------------------------------------------------------
struct CvtArgs {
  const float* src[12];
  short* dst;
  float* stats;
};

__global__ __launch_bounds__(256) void k0_setup(CvtArgs A) {
  const int cum[13] = {0, 49152, 110592, 126976, 143360, 159744, 176128,
                       241664, 307200, 372736, 438272, 471040, 479232};
  int b = blockIdx.x;
  if (b < 24) A.stats[b * 256 + threadIdx.x] = 0.0f;
  int base = b * 1024;
  int seg = 0;
#pragma unroll
  for (int t = 1; t < 12; ++t) seg += (base >= cum[t]) ? 1 : 0;
  const float* s = A.src[seg];
  int loc = base - cum[seg] + threadIdx.x * 4;
  float4 f = *(const float4*)(s + loc);
  int di = base + threadIdx.x * 4;
  int2 p;
  p.x = cvt2(f.x, f.y);
  p.y = cvt2(f.z, f.w);
  *(int2*)(A.dst + di) = p;
}

// ---------------------------------------------------------------------------
extern "C" void kernel_launch(void* const* d_in, const int* in_sizes, int n_in,
                              void* d_out, int out_size, void* d_ws, size_t ws_size,
                              hipStream_t stream) {
  (void)in_sizes; (void)n_in; (void)out_size; (void)ws_size;
  char* ws = (char*)d_ws;
  short* wb = (short*)ws;
  enum { O_PEP = 0, O_TCR = 49152, O_VP2T = 110592, O_OP2T = 126976,
         O_VT2P = 143360, O_OT2P = 159744, O_W1P = 176128, O_W2P = 241664,
         O_W1T = 307200, O_W2T = 372736, O_H1 = 438272, O_H2 = 471040 };
  float* stats = (float*)(ws + 958464);     // 6144 floats (sliced BN stats)
  short* h1f   = (short*)(ws + 983040);     // 1024 blocks * 8192 shorts
  short* h2f   = (short*)(ws + 17760256);   // 1024 blocks * 4096 shorts

  CvtArgs ca;
  ca.src[0]  = (const float*)d_in[1];   // w_pep
  ca.src[1]  = (const float*)d_in[3];   // w_tcr
  ca.src[2]  = (const float*)d_in[5];   // wv_p2t
  ca.src[3]  = (const float*)d_in[7];   // wo_p2t
  ca.src[4]  = (const float*)d_in[9];   // wv_t2p
  ca.src[5]  = (const float*)d_in[11];  // wo_t2p
  ca.src[6]  = (const float*)d_in[21];  // ffn_w1p
  ca.src[7]  = (const float*)d_in[23];  // ffn_w2p
  ca.src[8]  = (const float*)d_in[25];  // ffn_w1t
  ca.src[9]  = (const float*)d_in[27];  // ffn_w2t
  ca.src[10] = (const float*)d_in[29];  // w_h1
  ca.src[11] = (const float*)d_in[33];  // w_h2
  ca.dst = wb;
  ca.stats = stats;
  k0_setup<<<468, 256, 0, stream>>>(ca);

  K1Args a;
  a.x = (const float*)d_in[0];
  a.wpep = wb + O_PEP; a.wtcr = wb + O_TCR;
  a.wvp = wb + O_VP2T; a.wop = wb + O_OP2T;
  a.wvt = wb + O_VT2P; a.wot = wb + O_OT2P;
  a.w1p = wb + O_W1P;  a.w2p = wb + O_W2P;
  a.w1t = wb + O_W1T;  a.w2t = wb + O_W2T;
  a.wh1 = wb + O_H1;
  a.bpep = (const float*)d_in[2];
  a.btcr = (const float*)d_in[4];
  a.bvp = (const float*)d_in[6];
  a.bop = (const float*)d_in[8];
  a.bvt = (const float*)d_in[10];
  a.bot = (const float*)d_in[12];
  a.g1p = (const float*)d_in[13]; a.e1p = (const float*)d_in[14];
  a.g2p = (const float*)d_in[15]; a.e2p = (const float*)d_in[16];
  a.g1t = (const float*)d_in[17]; a.e1t = (const float*)d_in[18];
  a.g2t = (const float*)d_in[19]; a.e2t = (const float*)d_in[20];
  a.b1p = (const float*)d_in[22];
  a.b2p = (const float*)d_in[24];
  a.b1t = (const float*)d_in[26];
  a.b2t = (const float*)d_in[28];
  a.bh1 = (const float*)d_in[30];
  a.stats = stats;
  a.h1f = h1f;
  k1_body<<<1024, 256, 0, stream>>>(a);

  K2Args b;
  b.h1f = h1f;
  b.wh2 = wb + O_H2;
  b.bh2 = (const float*)d_in[34];
  b.bn1g = (const float*)d_in[31];
  b.bn1b = (const float*)d_in[32];
  b.stats = stats;
  b.h2f = h2f;
  k2_mid<<<1024, 256, 0, stream>>>(b);

  K3Args c;
  c.h2f = h2f;
  c.bn2g = (const float*)d_in[35];
  c.bn2b = (const float*)d_in[36];
  c.stats = stats;
  c.wout = (const float*)d_in[37];
  c.bout = (const float*)d_in[38];
  c.out = (float*)d_out;
  k3_out<<<1024, 256, 0, stream>>>(c);
}